// Round 19
// baseline (88.298 us; speedup 1.0000x reference)
//
#include <hip/hip_runtime.h>
#include <math.h>

#define N_NODES 50000
#define N_EDGES 800000
#define IN_DIM 256
#define HID 64
#define BKT 256
#define NBKT ((N_NODES + BKT - 1) / BKT)          // 196
#define CAP 8192                                  // ebuf slots per bucket (max real ~4400)
#define SEGC 5120                                 // LDS-cached entries per bucket
#define CHUNK 4096
#define NCH ((N_EDGES + CHUNK - 1) / CHUNK)       // 196
#define NGB ((N_NODES + 63) / 64)                 // 782

typedef short short8v __attribute__((ext_vector_type(8)));
typedef float f32x4 __attribute__((ext_vector_type(4)));
typedef float f32x2 __attribute__((ext_vector_type(2)));
typedef unsigned uint4v __attribute__((ext_vector_type(4)));

__device__ __forceinline__ unsigned short f2bf(float f) {
  unsigned u = __builtin_bit_cast(unsigned, f);
  u += 0x7FFFu + ((u >> 16) & 1u);  // RNE
  return (unsigned short)(u >> 16);
}
__device__ __forceinline__ unsigned pack2(float a, float b) {
  return (unsigned)f2bf(a) | ((unsigned)f2bf(b) << 16);
}
__device__ __forceinline__ float bfu_lo(unsigned u) {
  return __builtin_bit_cast(float, u << 16);
}
__device__ __forceinline__ float bfu_hi(unsigned u) {
  return __builtin_bit_cast(float, u & 0xFFFF0000u);
}
__device__ __forceinline__ unsigned char f2fp8(float f) {
  return (unsigned char)(__builtin_amdgcn_cvt_pk_fp8_f32(f, f, 0, false) & 0xFF);
}

// ---------------- prep: zero bcur + convert/transpose weights ----------------
__global__ void k_prep(int* __restrict__ bcur, const float* __restrict__ W1,
                       const float* __restrict__ W2, unsigned short* __restrict__ Wt1,
                       unsigned short* __restrict__ Wt2) {
  const int t = threadIdx.x;
  if (blockIdx.x == 0) {
    bcur[t] = 0;
  } else if (blockIdx.x == 1) {
    for (int j = 0; j < 64; ++j) {
      int lin = j * 256 + t;
      int k = lin >> 6, c = lin & 63;
      Wt1[c * 256 + k] = f2bf(W1[lin]);
    }
  } else {
    for (int j = 0; j < 16; ++j) {
      int lin = j * 256 + t;
      int k = lin >> 6, c = lin & 63;
      Wt2[c * 64 + k] = f2bf(W2[lin]);
    }
  }
}

// ---------------- fused: GEMM1 (blocks 0..NGB) || split (blocks NGB..) ----------------
// GEMM1: outA[r][c] = bf16( sum_k X[r][k]*W1[k][c] )  -- UNSCALED
// x staged via COALESCED cooperative load (64KB row-major tile, consecutive lanes
// -> consecutive 16B), all 16 loads issued before any consume (sched_barrier(0)
// pins ordering), converted to bf16 in-reg, parked in LDS Xb.
__global__ __launch_bounds__(256) void k_g1split(
    const float* __restrict__ X, const unsigned short* __restrict__ Wt1g,
    unsigned short* __restrict__ outA, const int* __restrict__ src,
    const int* __restrict__ dst, int* __restrict__ bcur, unsigned* __restrict__ ebuf) {
  __shared__ __align__(16) unsigned char smem[2 * 64 * (IN_DIM + 8) * 2];  // 67.6KB overlay
  const int t = threadIdx.x;
  if (blockIdx.x < NGB) {
    unsigned short(*Wl)[IN_DIM + 8] = (unsigned short(*)[IN_DIM + 8])smem;
    unsigned short(*Xb)[IN_DIM + 8] =
        (unsigned short(*)[IN_DIM + 8])(smem + 64 * (IN_DIM + 8) * 2);
    const int lane = t & 63, wv = t >> 6;
    const int row0 = blockIdx.x * 64;

    // issue ALL 16 coalesced x-loads (landing regs, no consumption yet)
    float4 xr[16];
#pragma unroll
    for (int j = 0; j < 16; ++j) {
      int lin = j * 256 + t;                 // 0..4095
      int rw = lin >> 6;                     // tile row 0..63
      int c4 = (lin & 63) * 4;               // f32 col
      int rg = row0 + rw;
      if (rg > N_NODES - 1) rg = N_NODES - 1;
      xr[j] = *reinterpret_cast<const float4*>(X + (size_t)rg * IN_DIM + c4);
    }
    __builtin_amdgcn_sched_barrier(0);  // pin: loads stay issued before consumes

    // stage Wt1 to LDS (its latency overlaps the x-loads above)
#pragma unroll
    for (int j = 0; j < 8; ++j) {
      int grp = j * 256 + t;
      int r = grp >> 5, c = (grp & 31) * 8;
      *reinterpret_cast<short8v*>(&Wl[r][c]) =
          *reinterpret_cast<const short8v*>(&Wt1g[r * IN_DIM + c]);
    }

    // convert + park x in LDS
#pragma unroll
    for (int j = 0; j < 16; ++j) {
      int lin = j * 256 + t;
      int rw = lin >> 6, c4 = (lin & 63) * 4;
      uint2 o;
      o.x = pack2(xr[j].x, xr[j].y);
      o.y = pack2(xr[j].z, xr[j].w);
      *reinterpret_cast<uint2*>(&Xb[rw][c4]) = o;
    }
    __syncthreads();

    const int kh = (lane >> 4) * 8;
    f32x4 acc[4] = {};
#pragma unroll
    for (int k0 = 0; k0 < 8; ++k0) {
      short8v a = *reinterpret_cast<const short8v*>(&Xb[wv * 16 + (lane & 15)][k0 * 32 + kh]);
#pragma unroll
      for (int n = 0; n < 4; ++n) {
        short8v b = *reinterpret_cast<const short8v*>(&Wl[n * 16 + (lane & 15)][k0 * 32 + kh]);
        acc[n] = __builtin_amdgcn_mfma_f32_16x16x32_bf16(a, b, acc[n], 0, 0, 0);
      }
    }

    const int r0 = row0 + wv * 16;
#pragma unroll
    for (int j = 0; j < 4; ++j) {
      int rr = r0 + (lane >> 4) * 4 + j;
      if (rr < N_NODES) {
#pragma unroll
        for (int n = 0; n < 4; ++n)
          outA[(size_t)rr * 64 + n * 16 + (lane & 15)] = f2bf(acc[n][j]);
      }
    }
  } else {
    // ---- split: LDS-staged bucket sort, dense write-out ----
    unsigned* stage = (unsigned*)smem;              // 4096 u32 = 16KB
    int* cnt   = (int*)(smem + 16384);              // 256
    int* off   = (int*)(smem + 17408);              // 256
    int* gbase = (int*)(smem + 18432);              // 256
    int* lcur  = (int*)(smem + 19456);              // 256
    const int base = (blockIdx.x - NGB) * CHUNK;
    const int valid = min(CHUNK, N_EDGES - base);

    cnt[t] = 0;
    __syncthreads();
#pragma unroll
    for (int i = 0; i < CHUNK / 256; ++i) {
      int e = base + i * 256 + t;
      if (e < N_EDGES) atomicAdd(&cnt[dst[e] >> 8], 1);
    }
    __syncthreads();
    {
      int c = cnt[t];
      off[t] = c;
      __syncthreads();
      for (int d = 1; d < 256; d <<= 1) {
        int v = off[t];
        int a = (t >= d) ? off[t - d] : 0;
        __syncthreads();
        off[t] = v + a;
        __syncthreads();
      }
      int ex = off[t] - c;
      off[t] = ex;
      lcur[t] = ex;
      gbase[t] = (t < NBKT && c) ? (t * CAP + atomicAdd(&bcur[t], c)) : 0;
    }
    __syncthreads();
#pragma unroll
    for (int i = 0; i < CHUNK / 256; ++i) {
      int e = base + i * 256 + t;
      if (e < N_EDGES) {
        int d = dst[e];
        int b = d >> 8;
        int p = atomicAdd(&lcur[b], 1);
        stage[p] = ((unsigned)b << 24) | ((unsigned)src[e] << 8) | (unsigned)(d & 255);
      }
    }
    __syncthreads();
    for (int i = t; i < valid; i += 256) {
      unsigned u = stage[i];
      int b = u >> 24;
      ebuf[gbase[b] + (i - off[b])] = u;
    }
  }
}

// ---------------- bucket: fine CSR (ushort col) + dinv + scaled fp8 h1' ----------------
__global__ void k_bucket(const unsigned* __restrict__ ebuf, const int* __restrict__ bcur,
                         int* __restrict__ rowptr, unsigned short* __restrict__ colidx,
                         float* __restrict__ dinv, const unsigned short* __restrict__ hbf,
                         unsigned char* __restrict__ h8) {
  __shared__ int sA[256];
  __shared__ int sB[256];
  __shared__ float sD[256];
  __shared__ unsigned seg[SEGC];  // 20KB
  const int b = blockIdx.x, t = threadIdx.x;

  const int cntb = bcur[b];
  const int sbeg = b * CAP;
  const int cached = cntb < SEGC ? cntb : SEGC;

  for (int i = t; i < cached; i += 256) seg[i] = ebuf[sbeg + i];

  sA[t] = (t < NBKT) ? bcur[t] : 0;
  __syncthreads();
  for (int d = 1; d < 256; d <<= 1) {
    int v = sA[t];
    int a = (t >= d) ? sA[t - d] : 0;
    __syncthreads();
    sA[t] = v + a;
    __syncthreads();
  }
  const int prefix = (b == 0) ? 0 : sA[b - 1];
  __syncthreads();

  sA[t] = 0;
  __syncthreads();
  for (int i = t; i < cached; i += 256) atomicAdd(&sA[seg[i] & 255], 1);
  for (int i = SEGC + t; i < cntb; i += 256) atomicAdd(&sA[ebuf[sbeg + i] & 255], 1);
  __syncthreads();
  const int myc = sA[t];
  sB[t] = myc;
  __syncthreads();
  for (int d = 1; d < 256; d <<= 1) {
    int v = sB[t];
    int a = (t >= d) ? sB[t - d] : 0;
    __syncthreads();
    sB[t] = v + a;
    __syncthreads();
  }
  const int node = b * BKT + t;
  const bool valid = node < N_NODES;
  const int ex = prefix + sB[t] - myc;
  const float dv = rsqrtf((float)(myc + 1));
  sD[t] = dv;
  if (valid) {
    rowptr[node] = ex;
    dinv[node] = dv;
    if (node == N_NODES - 1) rowptr[N_NODES] = N_EDGES;
  }
  __syncthreads();
  sB[t] = ex;
  __syncthreads();
  for (int i = t; i < cached; i += 256) {
    unsigned p = seg[i];
    int pos = atomicAdd(&sB[p & 255], 1);
    colidx[pos] = (unsigned short)((p >> 8) & 0xFFFFu);
  }
  for (int i = SEGC + t; i < cntb; i += 256) {
    unsigned p = ebuf[sbeg + i];
    int pos = atomicAdd(&sB[p & 255], 1);
    colidx[pos] = (unsigned short)((p >> 8) & 0xFFFFu);
  }

  // emit h1'[v] = fp8_e4m3( dinv[v] * h[v] ) -- 64B rows, L2-resident for agg1
  const int rsub = t >> 3, f8 = (t & 7) * 8;
#pragma unroll
  for (int g = 0; g < 8; ++g) {
    int lr = g * 32 + rsub;
    int nd = b * BKT + lr;
    if (nd < N_NODES) {
      float s = sD[lr];
      const unsigned short* hp = &hbf[(size_t)nd * 64 + f8];
      uint4 hv = *reinterpret_cast<const uint4*>(hp);
      float v0 = s * bfu_lo(hv.x), v1 = s * bfu_hi(hv.x);
      float v2 = s * bfu_lo(hv.y), v3 = s * bfu_hi(hv.y);
      float v4 = s * bfu_lo(hv.z), v5 = s * bfu_hi(hv.z);
      float v6 = s * bfu_lo(hv.w), v7 = s * bfu_hi(hv.w);
      int lo = 0, hi = 0;
      lo = __builtin_amdgcn_cvt_pk_fp8_f32(v0, v1, lo, false);
      lo = __builtin_amdgcn_cvt_pk_fp8_f32(v2, v3, lo, true);
      hi = __builtin_amdgcn_cvt_pk_fp8_f32(v4, v5, hi, false);
      hi = __builtin_amdgcn_cvt_pk_fp8_f32(v6, v7, hi, true);
      uint2 o;
      o.x = (unsigned)lo;
      o.y = (unsigned)hi;
      *reinterpret_cast<uint2*>(&h8[(size_t)nd * 64 + f8]) = o;
    }
  }
}

// ---------------- fp8 gather body ----------------
#define EDGE8(h8b, cc)                                                        \
  {                                                                           \
    uint2 w = *reinterpret_cast<const uint2*>(&h8b[(size_t)(cc) * 64 + f0]);  \
    f32x2 p0 = __builtin_amdgcn_cvt_pk_f32_fp8((int)w.x, false);              \
    f32x2 p1 = __builtin_amdgcn_cvt_pk_f32_fp8((int)w.x, true);               \
    f32x2 p2 = __builtin_amdgcn_cvt_pk_f32_fp8((int)w.y, false);              \
    f32x2 p3 = __builtin_amdgcn_cvt_pk_f32_fp8((int)w.y, true);               \
    acc0 += p0.x; acc1 += p0.y; acc2 += p1.x; acc3 += p1.y;                   \
    acc4 += p2.x; acc5 += p2.y; acc6 += p3.x; acc7 += p3.y;                   \
  }

// ushort col stream: 8 edges per 16B load
#define GATHER_F8(h8b)                                                        \
  int e = rowptr[v];                                                          \
  const int end = rowptr[v + 1];                                              \
  while (e < end && (e & 7)) { EDGE8(h8b, col[e]); ++e; }                     \
  for (; e + 8 <= end; e += 8) {                                              \
    short8v cw = *reinterpret_cast<const short8v*>(&col[e]);                  \
    EDGE8(h8b, (unsigned short)cw[0]); EDGE8(h8b, (unsigned short)cw[1]);     \
    EDGE8(h8b, (unsigned short)cw[2]); EDGE8(h8b, (unsigned short)cw[3]);     \
    EDGE8(h8b, (unsigned short)cw[4]); EDGE8(h8b, (unsigned short)cw[5]);     \
    EDGE8(h8b, (unsigned short)cw[6]); EDGE8(h8b, (unsigned short)cw[7]);     \
  }                                                                           \
  for (; e < end; ++e) { EDGE8(h8b, col[e]); }

// ---------------- agg1 (fp8 gather) + bias/relu + GEMM2 + fp8 h2' out ----------------
__global__ __launch_bounds__(256) void k_agg_gemm(
    const unsigned char* __restrict__ h8, const int* __restrict__ rowptr,
    const unsigned short* __restrict__ col, const float* __restrict__ dinv,
    const float* __restrict__ bias, const unsigned short* __restrict__ Wt2g,
    unsigned char* __restrict__ out8) {
  const int t = threadIdx.x, lane = t & 63, wv = t >> 6;
  const int g = lane >> 3, f0 = (lane & 7) * 8;
  const int vbase = blockIdx.x * 32;
  const int v = vbase + wv * 8 + g;
  const int lrow = wv * 8 + g;

  __shared__ unsigned short h1s[32][72];  // pad: 144B stride

  if (v < N_NODES) {
    const float sv = dinv[v];
    float acc0 = 0, acc1 = 0, acc2 = 0, acc3 = 0, acc4 = 0, acc5 = 0, acc6 = 0, acc7 = 0;
    EDGE8(h8, v)  // self-loop term
    GATHER_F8(h8)

    const float4 ba = *reinterpret_cast<const float4*>(&bias[f0]);
    const float4 bb = *reinterpret_cast<const float4*>(&bias[f0 + 4]);
    float v0 = fmaxf(fmaf(sv, acc0, ba.x), 0.0f);
    float v1 = fmaxf(fmaf(sv, acc1, ba.y), 0.0f);
    float v2 = fmaxf(fmaf(sv, acc2, ba.z), 0.0f);
    float v3 = fmaxf(fmaf(sv, acc3, ba.w), 0.0f);
    float v4 = fmaxf(fmaf(sv, acc4, bb.x), 0.0f);
    float v5 = fmaxf(fmaf(sv, acc5, bb.y), 0.0f);
    float v6 = fmaxf(fmaf(sv, acc6, bb.z), 0.0f);
    float v7 = fmaxf(fmaf(sv, acc7, bb.w), 0.0f);

    uint4 o;
    o.x = pack2(v0, v1); o.y = pack2(v2, v3);
    o.z = pack2(v4, v5); o.w = pack2(v6, v7);
    *reinterpret_cast<uint4*>(&h1s[lrow][f0]) = o;
  } else {
    uint4 z = {0, 0, 0, 0};
    *reinterpret_cast<uint4*>(&h1s[lrow][f0]) = z;
  }
  __syncthreads();

  // GEMM2: 32 nodes x 64 cols; wave wv owns cols [wv*16, wv*16+16); K=64.
  const int kh = (lane >> 4) * 8;
  f32x4 acc2r[2] = {};
#pragma unroll
  for (int rt = 0; rt < 2; ++rt) {
#pragma unroll
    for (int k0 = 0; k0 < 64; k0 += 32) {
      short8v a = *reinterpret_cast<const short8v*>(&h1s[rt * 16 + (lane & 15)][k0 + kh]);
      short8v b = *reinterpret_cast<const short8v*>(
          Wt2g + (size_t)(wv * 16 + (lane & 15)) * 64 + k0 + kh);
      acc2r[rt] = __builtin_amdgcn_mfma_f32_16x16x32_bf16(a, b, acc2r[rt], 0, 0, 0);
    }
  }
  // epilogue: h2'[r][c] = fp8( dinv[r] * acc )  (64B rows for agg2)
#pragma unroll
  for (int rt = 0; rt < 2; ++rt) {
#pragma unroll
    for (int j = 0; j < 4; ++j) {
      int vg = vbase + rt * 16 + (lane >> 4) * 4 + j;
      if (vg < N_NODES)
        out8[(size_t)vg * 64 + wv * 16 + (lane & 15)] = f2fp8(acc2r[rt][j] * dinv[vg]);
    }
  }
}

// ---------------- agg2 (fp8 gather) + classifier fused ----------------
__global__ __launch_bounds__(256) void k_agg_fin(
    const unsigned char* __restrict__ h8, const int* __restrict__ rowptr,
    const unsigned short* __restrict__ col, const float* __restrict__ dinv,
    const float* __restrict__ bias, const float* __restrict__ Wc,
    const float* __restrict__ bc, float* __restrict__ out) {
  const int t = threadIdx.x, lane = t & 63;
  const int g = lane >> 3, f0 = (lane & 7) * 8;
  const int v = blockIdx.x * 32 + (t >> 6) * 8 + g;
  if (v >= N_NODES) return;

  float acc0 = 0, acc1 = 0, acc2 = 0, acc3 = 0, acc4 = 0, acc5 = 0, acc6 = 0, acc7 = 0;
  EDGE8(h8, v)  // self-loop term
  GATHER_F8(h8)

  const float sv = dinv[v];
  const float4 ba = *reinterpret_cast<const float4*>(&bias[f0]);
  const float4 bb = *reinterpret_cast<const float4*>(&bias[f0 + 4]);
  const float4 wa = *reinterpret_cast<const float4*>(&Wc[f0]);
  const float4 wb = *reinterpret_cast<const float4*>(&Wc[f0 + 4]);
  float p = fmaxf(fmaf(sv, acc0, ba.x), 0.0f) * wa.x +
            fmaxf(fmaf(sv, acc1, ba.y), 0.0f) * wa.y +
            fmaxf(fmaf(sv, acc2, ba.z), 0.0f) * wa.z +
            fmaxf(fmaf(sv, acc3, ba.w), 0.0f) * wa.w +
            fmaxf(fmaf(sv, acc4, bb.x), 0.0f) * wb.x +
            fmaxf(fmaf(sv, acc5, bb.y), 0.0f) * wb.y +
            fmaxf(fmaf(sv, acc6, bb.z), 0.0f) * wb.z +
            fmaxf(fmaf(sv, acc7, bb.w), 0.0f) * wb.w;
  p += __shfl_xor(p, 1);
  p += __shfl_xor(p, 2);
  p += __shfl_xor(p, 4);
  if ((lane & 7) == 0) out[v] = 1.0f / (1.0f + expf(-(p + bc[0])));
}

extern "C" void kernel_launch(void* const* d_in, const int* in_sizes, int n_in,
                              void* d_out, int out_size, void* d_ws, size_t ws_size,
                              hipStream_t stream) {
  const float* x  = (const float*)d_in[0];
  const int*   ei = (const int*)d_in[1];
  const float* W1 = (const float*)d_in[2];
  const float* b1 = (const float*)d_in[3];
  const float* W2 = (const float*)d_in[4];
  const float* b2 = (const float*)d_in[5];
  const float* Wc = (const float*)d_in[6];
  const float* bc = (const float*)d_in[7];
  float* out = (float*)d_out;

  const int* src = ei;
  const int* dst = ei + N_EDGES;

  // workspace layout (u32 units)
  unsigned* w = (unsigned*)d_ws;
  int*   bcur   = (int*)(w + 0);                          // 256
  int*   rowptr = (int*)(w + 256);                        // 50432 (needs 50001)
  unsigned short* colidx = (unsigned short*)(w + 50688);  // 800000 ush = 400000 u32
  unsigned* ebuf = w + 450688;                            // 196*8192 = 1605632
  float* dinv   = (float*)(w + 2056320);                  // 50176
  unsigned short* Wt1g = (unsigned short*)(w + 2106496);  // 16384 ush
  unsigned short* Wt2g = (unsigned short*)(w + 2114688);  // 4096 ush
  unsigned short* A_bf = (unsigned short*)(w + 2116736);  // 3.2M ush (x@W1, unscaled)
  unsigned char*  A_f8 = (unsigned char*)(w + 3716736);   // 3.2M B (h1', fp8 scaled)
  unsigned char*  B_f8 = (unsigned char*)(w + 4516736);   // 3.2M B (h2', fp8 scaled)

  k_prep<<<3, 256, 0, stream>>>(bcur, W1, W2, Wt1g, Wt2g);
  // GEMM1 (coalesced LDS-staged x) runs concurrently with dense-split
  k_g1split<<<NGB + NCH, 256, 0, stream>>>(x, Wt1g, A_bf, src, dst, bcur, ebuf);
  // CSR build (ushort col) + dinv + fp8 h1' emission
  k_bucket<<<NBKT, 256, 0, stream>>>(ebuf, bcur, rowptr, colidx, dinv, A_bf, A_f8);

  const int NAB = (N_NODES + 31) / 32;  // 1563
  k_agg_gemm<<<NAB, 256, 0, stream>>>(A_f8, rowptr, colidx, dinv, b1, Wt2g, B_f8);
  k_agg_fin<<<NAB, 256, 0, stream>>>(B_f8, rowptr, colidx, dinv, b2, Wc, bc, out);
}

// Round 20
// 84.634 us; speedup vs baseline: 1.0433x; 1.0433x over previous
//
#include <hip/hip_runtime.h>
#include <math.h>

#define N_NODES 50000
#define N_EDGES 800000
#define IN_DIM 256
#define HID 64
#define BKT 256
#define NBKT ((N_NODES + BKT - 1) / BKT)          // 196
#define CAP 8192                                  // ebuf slots per bucket (max real ~4400)
#define SEGC 5120                                 // LDS-cached entries per bucket
#define CHUNK 4096
#define NCH ((N_EDGES + CHUNK - 1) / CHUNK)       // 196
#define NGB ((N_NODES + 63) / 64)                 // 782

typedef short short8v __attribute__((ext_vector_type(8)));
typedef float f32x4 __attribute__((ext_vector_type(4)));
typedef float f32x2 __attribute__((ext_vector_type(2)));
typedef unsigned uint4v __attribute__((ext_vector_type(4)));

__device__ __forceinline__ unsigned short f2bf(float f) {
  unsigned u = __builtin_bit_cast(unsigned, f);
  u += 0x7FFFu + ((u >> 16) & 1u);  // RNE
  return (unsigned short)(u >> 16);
}
__device__ __forceinline__ unsigned pack2(float a, float b) {
  return (unsigned)f2bf(a) | ((unsigned)f2bf(b) << 16);
}
__device__ __forceinline__ float bfu_lo(unsigned u) {
  return __builtin_bit_cast(float, u << 16);
}
__device__ __forceinline__ float bfu_hi(unsigned u) {
  return __builtin_bit_cast(float, u & 0xFFFF0000u);
}
__device__ __forceinline__ unsigned char f2fp8(float f) {
  return (unsigned char)(__builtin_amdgcn_cvt_pk_fp8_f32(f, f, 0, false) & 0xFF);
}

// ---------------- prep: zero bcur + convert/transpose weights ----------------
__global__ void k_prep(int* __restrict__ bcur, const float* __restrict__ W1,
                       const float* __restrict__ W2, unsigned short* __restrict__ Wt1,
                       unsigned short* __restrict__ Wt2) {
  const int t = threadIdx.x;
  if (blockIdx.x == 0) {
    bcur[t] = 0;
  } else if (blockIdx.x == 1) {
    for (int j = 0; j < 64; ++j) {
      int lin = j * 256 + t;
      int k = lin >> 6, c = lin & 63;
      Wt1[c * 256 + k] = f2bf(W1[lin]);
    }
  } else {
    for (int j = 0; j < 16; ++j) {
      int lin = j * 256 + t;
      int k = lin >> 6, c = lin & 63;
      Wt2[c * 64 + k] = f2bf(W2[lin]);
    }
  }
}

// ---------------- fused: GEMM1 || split, roles INTERLEAVED in dispatch order ----------------
// blockIdx%5==0 -> split chunk (196 blocks spread through dispatch);
// otherwise gemm tile gid = idx - idx/5 - 1 (782 blocks).
// GEMM1: outA[r][c] = bf16( sum_k X[r][k]*W1[k][c] )  -- UNSCALED
__global__ __launch_bounds__(256) void k_g1split(
    const float* __restrict__ X, const unsigned short* __restrict__ Wt1g,
    unsigned short* __restrict__ outA, const int* __restrict__ src,
    const int* __restrict__ dst, int* __restrict__ bcur, unsigned* __restrict__ ebuf) {
  __shared__ __align__(16) unsigned char smem[(64 * (IN_DIM + 8)) * 2];  // 33.8KB overlay
  const int t = threadIdx.x;
  const int bi = blockIdx.x;
  if ((bi % 5) != 0) {
    const int gid = bi - bi / 5 - 1;  // 0..781
    unsigned short(*Wl)[IN_DIM + 8] = (unsigned short(*)[IN_DIM + 8])smem;
    const int lane = t & 63, wv = t >> 6;
#pragma unroll
    for (int j = 0; j < 8; ++j) {
      int grp = j * 256 + t;
      int r = grp >> 5, c = (grp & 31) * 8;
      *reinterpret_cast<short8v*>(&Wl[r][c]) =
          *reinterpret_cast<const short8v*>(&Wt1g[r * IN_DIM + c]);
    }
    const int row0 = gid * 64;
    int r = row0 + wv * 16 + (lane & 15);
    if (r > N_NODES - 1) r = N_NODES - 1;  // clamp (stores guarded)
    const int kh = (lane >> 4) * 8;

    uint4v ap[8];
#pragma unroll
    for (int k0 = 0; k0 < 8; ++k0) {
      const float* Xp = X + (size_t)r * IN_DIM + k0 * 32 + kh;
      const float4 x0 = *reinterpret_cast<const float4*>(Xp);
      const float4 x1 = *reinterpret_cast<const float4*>(Xp + 4);
      uint4v p;
      p.x = pack2(x0.x, x0.y); p.y = pack2(x0.z, x0.w);
      p.z = pack2(x1.x, x1.y); p.w = pack2(x1.z, x1.w);
      ap[k0] = p;
    }
    __syncthreads();

    f32x4 acc[4] = {};
#pragma unroll
    for (int k0 = 0; k0 < 8; ++k0) {
      short8v a = __builtin_bit_cast(short8v, ap[k0]);
#pragma unroll
      for (int n = 0; n < 4; ++n) {
        short8v b = *reinterpret_cast<const short8v*>(&Wl[n * 16 + (lane & 15)][k0 * 32 + kh]);
        acc[n] = __builtin_amdgcn_mfma_f32_16x16x32_bf16(a, b, acc[n], 0, 0, 0);
      }
    }

    const int r0 = row0 + wv * 16;
#pragma unroll
    for (int j = 0; j < 4; ++j) {
      int rr = r0 + (lane >> 4) * 4 + j;
      if (rr < N_NODES) {
#pragma unroll
        for (int n = 0; n < 4; ++n)
          outA[(size_t)rr * 64 + n * 16 + (lane & 15)] = f2bf(acc[n][j]);
      }
    }
  } else {
    // ---- split chunk sid = bi/5: LDS-staged bucket sort, dense write-out ----
    const int sid = bi / 5;  // 0..195
    unsigned* stage = (unsigned*)smem;              // 4096 u32 = 16KB
    int* cnt   = (int*)(smem + 16384);              // 256
    int* off   = (int*)(smem + 17408);              // 256
    int* gbase = (int*)(smem + 18432);              // 256
    int* lcur  = (int*)(smem + 19456);              // 256
    const int base = sid * CHUNK;
    const int valid = min(CHUNK, N_EDGES - base);

    cnt[t] = 0;
    __syncthreads();
#pragma unroll
    for (int i = 0; i < CHUNK / 256; ++i) {
      int e = base + i * 256 + t;
      if (e < N_EDGES) atomicAdd(&cnt[dst[e] >> 8], 1);
    }
    __syncthreads();
    {
      int c = cnt[t];
      off[t] = c;
      __syncthreads();
      for (int d = 1; d < 256; d <<= 1) {
        int v = off[t];
        int a = (t >= d) ? off[t - d] : 0;
        __syncthreads();
        off[t] = v + a;
        __syncthreads();
      }
      int ex = off[t] - c;
      off[t] = ex;
      lcur[t] = ex;
      gbase[t] = (t < NBKT && c) ? (t * CAP + atomicAdd(&bcur[t], c)) : 0;
    }
    __syncthreads();
#pragma unroll
    for (int i = 0; i < CHUNK / 256; ++i) {
      int e = base + i * 256 + t;
      if (e < N_EDGES) {
        int d = dst[e];
        int b = d >> 8;
        int p = atomicAdd(&lcur[b], 1);
        stage[p] = ((unsigned)b << 24) | ((unsigned)src[e] << 8) | (unsigned)(d & 255);
      }
    }
    __syncthreads();
    for (int i = t; i < valid; i += 256) {
      unsigned u = stage[i];
      int b = u >> 24;
      ebuf[gbase[b] + (i - off[b])] = u;
    }
  }
}

// ---------------- bucket: fine CSR (ushort col) + dinv + scaled fp8 h1' ----------------
__global__ void k_bucket(const unsigned* __restrict__ ebuf, const int* __restrict__ bcur,
                         int* __restrict__ rowptr, unsigned short* __restrict__ colidx,
                         float* __restrict__ dinv, const unsigned short* __restrict__ hbf,
                         unsigned char* __restrict__ h8) {
  __shared__ int sA[256];
  __shared__ int sB[256];
  __shared__ float sD[256];
  __shared__ unsigned seg[SEGC];  // 20KB
  const int b = blockIdx.x, t = threadIdx.x;

  const int cntb = bcur[b];
  const int sbeg = b * CAP;
  const int cached = cntb < SEGC ? cntb : SEGC;

  for (int i = t; i < cached; i += 256) seg[i] = ebuf[sbeg + i];

  sA[t] = (t < NBKT) ? bcur[t] : 0;
  __syncthreads();
  for (int d = 1; d < 256; d <<= 1) {
    int v = sA[t];
    int a = (t >= d) ? sA[t - d] : 0;
    __syncthreads();
    sA[t] = v + a;
    __syncthreads();
  }
  const int prefix = (b == 0) ? 0 : sA[b - 1];
  __syncthreads();

  sA[t] = 0;
  __syncthreads();
  for (int i = t; i < cached; i += 256) atomicAdd(&sA[seg[i] & 255], 1);
  for (int i = SEGC + t; i < cntb; i += 256) atomicAdd(&sA[ebuf[sbeg + i] & 255], 1);
  __syncthreads();
  const int myc = sA[t];
  sB[t] = myc;
  __syncthreads();
  for (int d = 1; d < 256; d <<= 1) {
    int v = sB[t];
    int a = (t >= d) ? sB[t - d] : 0;
    __syncthreads();
    sB[t] = v + a;
    __syncthreads();
  }
  const int node = b * BKT + t;
  const bool valid = node < N_NODES;
  const int ex = prefix + sB[t] - myc;
  const float dv = rsqrtf((float)(myc + 1));
  sD[t] = dv;
  if (valid) {
    rowptr[node] = ex;
    dinv[node] = dv;
    if (node == N_NODES - 1) rowptr[N_NODES] = N_EDGES;
  }
  __syncthreads();
  sB[t] = ex;
  __syncthreads();
  for (int i = t; i < cached; i += 256) {
    unsigned p = seg[i];
    int pos = atomicAdd(&sB[p & 255], 1);
    colidx[pos] = (unsigned short)((p >> 8) & 0xFFFFu);
  }
  for (int i = SEGC + t; i < cntb; i += 256) {
    unsigned p = ebuf[sbeg + i];
    int pos = atomicAdd(&sB[p & 255], 1);
    colidx[pos] = (unsigned short)((p >> 8) & 0xFFFFu);
  }

  // emit h1'[v] = fp8_e4m3( dinv[v] * h[v] ) -- 64B rows, L2-resident for agg1
  const int rsub = t >> 3, f8 = (t & 7) * 8;
#pragma unroll
  for (int g = 0; g < 8; ++g) {
    int lr = g * 32 + rsub;
    int nd = b * BKT + lr;
    if (nd < N_NODES) {
      float s = sD[lr];
      const unsigned short* hp = &hbf[(size_t)nd * 64 + f8];
      uint4 hv = *reinterpret_cast<const uint4*>(hp);
      float v0 = s * bfu_lo(hv.x), v1 = s * bfu_hi(hv.x);
      float v2 = s * bfu_lo(hv.y), v3 = s * bfu_hi(hv.y);
      float v4 = s * bfu_lo(hv.z), v5 = s * bfu_hi(hv.z);
      float v6 = s * bfu_lo(hv.w), v7 = s * bfu_hi(hv.w);
      int lo = 0, hi = 0;
      lo = __builtin_amdgcn_cvt_pk_fp8_f32(v0, v1, lo, false);
      lo = __builtin_amdgcn_cvt_pk_fp8_f32(v2, v3, lo, true);
      hi = __builtin_amdgcn_cvt_pk_fp8_f32(v4, v5, hi, false);
      hi = __builtin_amdgcn_cvt_pk_fp8_f32(v6, v7, hi, true);
      uint2 o;
      o.x = (unsigned)lo;
      o.y = (unsigned)hi;
      *reinterpret_cast<uint2*>(&h8[(size_t)nd * 64 + f8]) = o;
    }
  }
}

// ---------------- fp8 gather body ----------------
#define EDGE8(h8b, cc)                                                        \
  {                                                                           \
    uint2 w = *reinterpret_cast<const uint2*>(&h8b[(size_t)(cc) * 64 + f0]);  \
    f32x2 p0 = __builtin_amdgcn_cvt_pk_f32_fp8((int)w.x, false);              \
    f32x2 p1 = __builtin_amdgcn_cvt_pk_f32_fp8((int)w.x, true);               \
    f32x2 p2 = __builtin_amdgcn_cvt_pk_f32_fp8((int)w.y, false);              \
    f32x2 p3 = __builtin_amdgcn_cvt_pk_f32_fp8((int)w.y, true);               \
    acc0 += p0.x; acc1 += p0.y; acc2 += p1.x; acc3 += p1.y;                   \
    acc4 += p2.x; acc5 += p2.y; acc6 += p3.x; acc7 += p3.y;                   \
  }

// ushort col stream: 8 edges per 16B load
#define GATHER_F8(h8b)                                                        \
  int e = rowptr[v];                                                          \
  const int end = rowptr[v + 1];                                              \
  while (e < end && (e & 7)) { EDGE8(h8b, col[e]); ++e; }                     \
  for (; e + 8 <= end; e += 8) {                                              \
    short8v cw = *reinterpret_cast<const short8v*>(&col[e]);                  \
    EDGE8(h8b, (unsigned short)cw[0]); EDGE8(h8b, (unsigned short)cw[1]);     \
    EDGE8(h8b, (unsigned short)cw[2]); EDGE8(h8b, (unsigned short)cw[3]);     \
    EDGE8(h8b, (unsigned short)cw[4]); EDGE8(h8b, (unsigned short)cw[5]);     \
    EDGE8(h8b, (unsigned short)cw[6]); EDGE8(h8b, (unsigned short)cw[7]);     \
  }                                                                           \
  for (; e < end; ++e) { EDGE8(h8b, col[e]); }

// ---------------- agg1 (fp8 gather) + bias/relu + GEMM2 + fp8 h2' out ----------------
__global__ __launch_bounds__(256) void k_agg_gemm(
    const unsigned char* __restrict__ h8, const int* __restrict__ rowptr,
    const unsigned short* __restrict__ col, const float* __restrict__ dinv,
    const float* __restrict__ bias, const unsigned short* __restrict__ Wt2g,
    unsigned char* __restrict__ out8) {
  const int t = threadIdx.x, lane = t & 63, wv = t >> 6;
  const int g = lane >> 3, f0 = (lane & 7) * 8;
  const int vbase = blockIdx.x * 32;
  const int v = vbase + wv * 8 + g;
  const int lrow = wv * 8 + g;

  __shared__ unsigned short h1s[32][72];  // pad: 144B stride

  if (v < N_NODES) {
    const float sv = dinv[v];
    float acc0 = 0, acc1 = 0, acc2 = 0, acc3 = 0, acc4 = 0, acc5 = 0, acc6 = 0, acc7 = 0;
    EDGE8(h8, v)  // self-loop term
    GATHER_F8(h8)

    const float4 ba = *reinterpret_cast<const float4*>(&bias[f0]);
    const float4 bb = *reinterpret_cast<const float4*>(&bias[f0 + 4]);
    float v0 = fmaxf(fmaf(sv, acc0, ba.x), 0.0f);
    float v1 = fmaxf(fmaf(sv, acc1, ba.y), 0.0f);
    float v2 = fmaxf(fmaf(sv, acc2, ba.z), 0.0f);
    float v3 = fmaxf(fmaf(sv, acc3, ba.w), 0.0f);
    float v4 = fmaxf(fmaf(sv, acc4, bb.x), 0.0f);
    float v5 = fmaxf(fmaf(sv, acc5, bb.y), 0.0f);
    float v6 = fmaxf(fmaf(sv, acc6, bb.z), 0.0f);
    float v7 = fmaxf(fmaf(sv, acc7, bb.w), 0.0f);

    uint4 o;
    o.x = pack2(v0, v1); o.y = pack2(v2, v3);
    o.z = pack2(v4, v5); o.w = pack2(v6, v7);
    *reinterpret_cast<uint4*>(&h1s[lrow][f0]) = o;
  } else {
    uint4 z = {0, 0, 0, 0};
    *reinterpret_cast<uint4*>(&h1s[lrow][f0]) = z;
  }
  __syncthreads();

  // GEMM2: 32 nodes x 64 cols; wave wv owns cols [wv*16, wv*16+16); K=64.
  const int kh = (lane >> 4) * 8;
  f32x4 acc2r[2] = {};
#pragma unroll
  for (int rt = 0; rt < 2; ++rt) {
#pragma unroll
    for (int k0 = 0; k0 < 64; k0 += 32) {
      short8v a = *reinterpret_cast<const short8v*>(&h1s[rt * 16 + (lane & 15)][k0 + kh]);
      short8v b = *reinterpret_cast<const short8v*>(
          Wt2g + (size_t)(wv * 16 + (lane & 15)) * 64 + k0 + kh);
      acc2r[rt] = __builtin_amdgcn_mfma_f32_16x16x32_bf16(a, b, acc2r[rt], 0, 0, 0);
    }
  }
  // epilogue: h2'[r][c] = fp8( dinv[r] * acc )  (64B rows for agg2)
#pragma unroll
  for (int rt = 0; rt < 2; ++rt) {
#pragma unroll
    for (int j = 0; j < 4; ++j) {
      int vg = vbase + rt * 16 + (lane >> 4) * 4 + j;
      if (vg < N_NODES)
        out8[(size_t)vg * 64 + wv * 16 + (lane & 15)] = f2fp8(acc2r[rt][j] * dinv[vg]);
    }
  }
}

// ---------------- agg2 (fp8 gather) + classifier fused ----------------
__global__ __launch_bounds__(256) void k_agg_fin(
    const unsigned char* __restrict__ h8, const int* __restrict__ rowptr,
    const unsigned short* __restrict__ col, const float* __restrict__ dinv,
    const float* __restrict__ bias, const float* __restrict__ Wc,
    const float* __restrict__ bc, float* __restrict__ out) {
  const int t = threadIdx.x, lane = t & 63;
  const int g = lane >> 3, f0 = (lane & 7) * 8;
  const int v = blockIdx.x * 32 + (t >> 6) * 8 + g;
  if (v >= N_NODES) return;

  float acc0 = 0, acc1 = 0, acc2 = 0, acc3 = 0, acc4 = 0, acc5 = 0, acc6 = 0, acc7 = 0;
  EDGE8(h8, v)  // self-loop term
  GATHER_F8(h8)

  const float sv = dinv[v];
  const float4 ba = *reinterpret_cast<const float4*>(&bias[f0]);
  const float4 bb = *reinterpret_cast<const float4*>(&bias[f0 + 4]);
  const float4 wa = *reinterpret_cast<const float4*>(&Wc[f0]);
  const float4 wb = *reinterpret_cast<const float4*>(&Wc[f0 + 4]);
  float p = fmaxf(fmaf(sv, acc0, ba.x), 0.0f) * wa.x +
            fmaxf(fmaf(sv, acc1, ba.y), 0.0f) * wa.y +
            fmaxf(fmaf(sv, acc2, ba.z), 0.0f) * wa.z +
            fmaxf(fmaf(sv, acc3, ba.w), 0.0f) * wa.w +
            fmaxf(fmaf(sv, acc4, bb.x), 0.0f) * wb.x +
            fmaxf(fmaf(sv, acc5, bb.y), 0.0f) * wb.y +
            fmaxf(fmaf(sv, acc6, bb.z), 0.0f) * wb.z +
            fmaxf(fmaf(sv, acc7, bb.w), 0.0f) * wb.w;
  p += __shfl_xor(p, 1);
  p += __shfl_xor(p, 2);
  p += __shfl_xor(p, 4);
  if ((lane & 7) == 0) out[v] = 1.0f / (1.0f + expf(-(p + bc[0])));
}

extern "C" void kernel_launch(void* const* d_in, const int* in_sizes, int n_in,
                              void* d_out, int out_size, void* d_ws, size_t ws_size,
                              hipStream_t stream) {
  const float* x  = (const float*)d_in[0];
  const int*   ei = (const int*)d_in[1];
  const float* W1 = (const float*)d_in[2];
  const float* b1 = (const float*)d_in[3];
  const float* W2 = (const float*)d_in[4];
  const float* b2 = (const float*)d_in[5];
  const float* Wc = (const float*)d_in[6];
  const float* bc = (const float*)d_in[7];
  float* out = (float*)d_out;

  const int* src = ei;
  const int* dst = ei + N_EDGES;

  // workspace layout (u32 units)
  unsigned* w = (unsigned*)d_ws;
  int*   bcur   = (int*)(w + 0);                          // 256
  int*   rowptr = (int*)(w + 256);                        // 50432 (needs 50001)
  unsigned short* colidx = (unsigned short*)(w + 50688);  // 800000 ush = 400000 u32
  unsigned* ebuf = w + 450688;                            // 196*8192 = 1605632
  float* dinv   = (float*)(w + 2056320);                  // 50176
  unsigned short* Wt1g = (unsigned short*)(w + 2106496);  // 16384 ush
  unsigned short* Wt2g = (unsigned short*)(w + 2114688);  // 4096 ush
  unsigned short* A_bf = (unsigned short*)(w + 2116736);  // 3.2M ush (x@W1, unscaled)
  unsigned char*  A_f8 = (unsigned char*)(w + 3716736);   // 3.2M B (h1', fp8 scaled)
  unsigned char*  B_f8 = (unsigned char*)(w + 4516736);   // 3.2M B (h2', fp8 scaled)

  k_prep<<<3, 256, 0, stream>>>(bcur, W1, W2, Wt1g, Wt2g);
  // GEMM1 and split roles interleaved through dispatch order for true overlap
  k_g1split<<<NGB + NCH, 256, 0, stream>>>(x, Wt1g, A_bf, src, dst, bcur, ebuf);
  // CSR build (ushort col) + dinv + fp8 h1' emission
  k_bucket<<<NBKT, 256, 0, stream>>>(ebuf, bcur, rowptr, colidx, dinv, A_bf, A_f8);

  const int NAB = (N_NODES + 31) / 32;  // 1563
  k_agg_gemm<<<NAB, 256, 0, stream>>>(A_f8, rowptr, colidx, dinv, b1, Wt2g, B_f8);
  k_agg_fin<<<NAB, 256, 0, stream>>>(B_f8, rowptr, colidx, dinv, b2, Wc, bc, out);
}